// Round 7
// baseline (279.987 us; speedup 1.0000x reference)
//
#include <hip/hip_runtime.h>
#include <math.h>

typedef unsigned short u16;
typedef __attribute__((ext_vector_type(8))) short bf16x8;
typedef __attribute__((ext_vector_type(4))) float f32x4;

#define N 2048
#define D 256
#define PAIRS 8
#define NO 2049
#define NEGMIN  -3.40282347e38f
#define MASKVAL -3.0e38f          // stored sentinel: finite in bf16
#define LDA 72                    // padded LDS row stride (u16) for k_proj

// ws float region (float offsets within wsf)
#define WS_LS0   0
#define WS_LS1   (1*PAIRS*N)
#define WS_LSN0  (2*PAIRS*N)
#define WS_LSN1  (3*PAIRS*N)
#define WS_RMAX  (4*PAIRS*N)
#define WS_RLSE  (5*PAIRS*N)
#define WS_CMAX  (6*PAIRS*N)
#define WS_CLSE  (7*PAIRS*N)
#define WS_RPM   (8*PAIRS*N)               // row partials max [PAIRS][16][N]
#define WS_RPS   (WS_RPM + PAIRS*16*N)
#define WS_CPM   (WS_RPS + PAIRS*16*N)     // col partials max [PAIRS][16][N]
#define WS_CPS   (WS_CPM + PAIRS*16*N)
#define WS_F_COUNT (WS_CPS + PAIRS*16*N)

__device__ __forceinline__ float b2f(u16 u) {
    return __uint_as_float(((unsigned)u) << 16);
}
__device__ __forceinline__ u16 f2b(float f) {  // RNE f32->bf16 (finite in)
    unsigned x = __float_as_uint(f);
    x += 0x7FFFu + ((x >> 16) & 1u);
    return (u16)(x >> 16);
}
__device__ __forceinline__ unsigned pk2(float a, float b) {
    return (unsigned)f2b(a) | ((unsigned)f2b(b) << 16);
}
__device__ __forceinline__ float logsig(float x) {
    return fminf(x, 0.f) - log1pf(expf(-fabsf(x)));
}
__device__ __forceinline__ void online1(float& m, float& s, float x) {
    float nm = fmaxf(m, x);
    float e = __expf(fminf(m, x) - nm);
    s = (x > m) ? s * e + 1.f : s + e;
    m = nm;
}
__device__ __forceinline__ void onmerge(float& m, float& s, float om, float os) {
    float nm = fmaxf(m, om);
    s = s * __expf(m - nm) + os * __expf(om - nm);
    m = nm;
}
// async global->LDS, 16B per lane; lds base must be wave-uniform
__device__ __forceinline__ void gl_lds16(const u16* g, u16* l) {
    __builtin_amdgcn_global_load_lds(
        (const __attribute__((address_space(1))) unsigned int*)g,
        (__attribute__((address_space(3))) unsigned int*)l,
        16, 0, 0);
}

// ---- projection GEMM via MFMA + fused matchability ----
// mdesc[r,j] = bf16((sum_k desc[r,k]*W[j,k] + bias[j]) * 0.25)
// blockIdx.y==0 blocks also compute m[r] = desc[r]·mw + mb and the logsig arrays.
__global__ __launch_bounds__(256) void k_proj_mfma(const float* __restrict__ A,
                                                   const float* __restrict__ W,
                                                   const float* __restrict__ bias,
                                                   const float* __restrict__ mw,
                                                   const float* __restrict__ mb,
                                                   u16* __restrict__ mdesc,
                                                   float* __restrict__ wsf) {
    __shared__ u16 As[128 * LDA];
    __shared__ u16 Bs[128 * LDA];
    int r0 = blockIdx.x * 128, c0 = blockIdx.y * 128;
    int tid = threadIdx.x;
    int w = tid >> 6, lane = tid & 63;
    int ln = lane & 15, q = lane >> 4;
    int wr0 = (w >> 1) * 64, wc0 = (w & 1) * 64;
    f32x4 zero = {0.f, 0.f, 0.f, 0.f};
    f32x4 acc[4][4];
    #pragma unroll
    for (int a = 0; a < 4; ++a)
        #pragma unroll
        for (int b = 0; b < 4; ++b) acc[a][b] = zero;
    float mdot[4] = {0.f, 0.f, 0.f, 0.f};
    int domatch = (blockIdx.y == 0);

    for (int kb = 0; kb < D; kb += 64) {
        __syncthreads();
        #pragma unroll
        for (int t = 0; t < 4; ++t) {
            int c = t * 256 + tid;          // chunk (8 bf16 each)
            int row = c >> 3, part = c & 7;
            const float* ap = A + (size_t)(r0 + row) * D + kb + part * 8;
            float4 f0 = *(const float4*)ap;
            float4 f1 = *(const float4*)(ap + 4);
            uint4 va;
            va.x = pk2(f0.x, f0.y); va.y = pk2(f0.z, f0.w);
            va.z = pk2(f1.x, f1.y); va.w = pk2(f1.z, f1.w);
            *(uint4*)&As[row * LDA + part * 8] = va;
            if (domatch) {
                float4 w0 = *(const float4*)(mw + kb + part * 8);
                float4 w1 = *(const float4*)(mw + kb + part * 8 + 4);
                mdot[t] += f0.x*w0.x + f0.y*w0.y + f0.z*w0.z + f0.w*w0.w
                         + f1.x*w1.x + f1.y*w1.y + f1.z*w1.z + f1.w*w1.w;
            }
            const float* bp = W + (size_t)(c0 + row) * D + kb + part * 8;
            float4 g0 = *(const float4*)bp;
            float4 g1 = *(const float4*)(bp + 4);
            uint4 vb;
            vb.x = pk2(g0.x, g0.y); vb.y = pk2(g0.z, g0.w);
            vb.z = pk2(g1.x, g1.y); vb.w = pk2(g1.z, g1.w);
            *(uint4*)&Bs[row * LDA + part * 8] = vb;
        }
        __syncthreads();
        #pragma unroll
        for (int kk = 0; kk < 64; kk += 32) {
            bf16x8 af[4], bf[4];
            #pragma unroll
            for (int ri = 0; ri < 4; ++ri)
                af[ri] = *(const bf16x8*)&As[(wr0 + ri*16 + ln) * LDA + kk + q*8];
            #pragma unroll
            for (int ci = 0; ci < 4; ++ci)
                bf[ci] = *(const bf16x8*)&Bs[(wc0 + ci*16 + ln) * LDA + kk + q*8];
            #pragma unroll
            for (int ri = 0; ri < 4; ++ri)
                #pragma unroll
                for (int ci = 0; ci < 4; ++ci)
                    acc[ri][ci] = __builtin_amdgcn_mfma_f32_16x16x32_bf16(af[ri], bf[ci], acc[ri][ci], 0, 0, 0);
        }
    }
    if (domatch) {
        #pragma unroll
        for (int t = 0; t < 4; ++t) {
            float s = mdot[t];
            s += __shfl_xor(s, 1, 64);
            s += __shfl_xor(s, 2, 64);
            s += __shfl_xor(s, 4, 64);
            if ((tid & 7) == 0) {
                int row_g = r0 + t * 32 + (tid >> 3);
                float m = s + mb[0];
                int b = row_g >> 11;
                int i = row_g & (N - 1);
                int pp = b >> 1, sid = b & 1;
                float ls = logsig(m), lsn = logsig(-m);
                if (sid == 0) { wsf[WS_LS0 + pp*N + i] = ls; wsf[WS_LSN0 + pp*N + i] = lsn; }
                else          { wsf[WS_LS1 + pp*N + i] = ls; wsf[WS_LSN1 + pp*N + i] = lsn; }
            }
        }
    }
    #pragma unroll
    for (int ri = 0; ri < 4; ++ri) {
        #pragma unroll
        for (int reg = 0; reg < 4; ++reg) {
            int row = r0 + wr0 + ri*16 + q*4 + reg;
            #pragma unroll
            for (int ci = 0; ci < 4; ++ci) {
                int col = c0 + wc0 + ci*16 + ln;
                float v = (acc[ri][ci][reg] + bias[col]) * 0.25f;
                mdesc[(size_t)row * D + col] = f2b(v);
            }
        }
    }
}

// ---- similarity GEMM via MFMA (global_load_lds staging) + fused mask + lse partials ----
__global__ __launch_bounds__(256) void k_sim_mfma(const u16* __restrict__ mdesc,
                                                  const int* __restrict__ mask,
                                                  u16* __restrict__ out,
                                                  float* __restrict__ wsf) {
    __shared__ u16 As[128 * 64];    // unpadded: lane-contiguous for global_load_lds
    __shared__ u16 Bs[128 * 64];
    __shared__ float rpm[128][2], rps[128][2];
    __shared__ float cpm[128][2], cps[128][2];
    int p = blockIdx.z;
    const u16* A  = mdesc + (size_t)(2*p) * N * D;
    const u16* Bm = mdesc + (size_t)(2*p + 1) * N * D;
    int r0 = blockIdx.x * 128, c0 = blockIdx.y * 128;
    int tid = threadIdx.x;
    int w = tid >> 6, lane = tid & 63;
    int ln = lane & 15, q = lane >> 4;
    int wr0 = (w >> 1) * 64, wc0 = (w & 1) * 64;
    int lrow = lane >> 3, lpart = lane & 7;     // staging: 8 rows x 8 x 16B per chunk
    f32x4 zero = {0.f, 0.f, 0.f, 0.f};
    f32x4 acc[4][4];
    #pragma unroll
    for (int a = 0; a < 4; ++a)
        #pragma unroll
        for (int b = 0; b < 4; ++b) acc[a][b] = zero;

    for (int kb = 0; kb < D; kb += 64) {
        __syncthreads();
        #pragma unroll
        for (int t = 0; t < 4; ++t) {
            int chunk = w * 4 + t;              // 0..15, 8 rows each
            int row = chunk * 8 + lrow;
            gl_lds16(A  + (size_t)(r0 + row) * D + kb + lpart * 8, &As[chunk * 512]);
            gl_lds16(Bm + (size_t)(c0 + row) * D + kb + lpart * 8, &Bs[chunk * 512]);
        }
        __syncthreads();
        #pragma unroll
        for (int kk = 0; kk < 64; kk += 32) {
            bf16x8 af[4], bf[4];
            #pragma unroll
            for (int ri = 0; ri < 4; ++ri)
                af[ri] = *(const bf16x8*)&As[(wr0 + ri*16 + ln) * 64 + kk + q*8];
            #pragma unroll
            for (int ci = 0; ci < 4; ++ci)
                bf[ci] = *(const bf16x8*)&Bs[(wc0 + ci*16 + ln) * 64 + kk + q*8];
            #pragma unroll
            for (int ri = 0; ri < 4; ++ri)
                #pragma unroll
                for (int ci = 0; ci < 4; ++ci)
                    acc[ri][ci] = __builtin_amdgcn_mfma_f32_16x16x32_bf16(af[ri], bf[ci], acc[ri][ci], 0, 0, 0);
        }
    }
    const int* m0 = mask + (size_t)(2*p) * N;
    const int* m1 = mask + (size_t)(2*p + 1) * N;
    u16* outp = out + (size_t)p * NO * NO;
    int mcol[4];
    #pragma unroll
    for (int ci = 0; ci < 4; ++ci) mcol[ci] = m1[c0 + wc0 + ci*16 + ln];
    // apply mask in place + store bf16
    #pragma unroll
    for (int ri = 0; ri < 4; ++ri) {
        #pragma unroll
        for (int reg = 0; reg < 4; ++reg) {
            int row = r0 + wr0 + ri*16 + q*4 + reg;
            int mr = m0[row];
            size_t base = (size_t)row * NO + c0 + wc0 + ln;
            #pragma unroll
            for (int ci = 0; ci < 4; ++ci) {
                float v = (mr && mcol[ci]) ? acc[ri][ci][reg] : MASKVAL;
                acc[ri][ci][reg] = v;
                outp[base + ci*16] = f2b(v);
            }
        }
    }
    // row partials: per (ri,reg) row, over this wave's 64 cols
    #pragma unroll
    for (int ri = 0; ri < 4; ++ri) {
        #pragma unroll
        for (int reg = 0; reg < 4; ++reg) {
            float m = acc[ri][0][reg], s = 1.f;
            online1(m, s, acc[ri][1][reg]);
            online1(m, s, acc[ri][2][reg]);
            online1(m, s, acc[ri][3][reg]);
            #pragma unroll
            for (int off = 1; off <= 8; off <<= 1) {
                float om = __shfl_xor(m, off, 64);
                float os = __shfl_xor(s, off, 64);
                onmerge(m, s, om, os);
            }
            if (ln == 0) {
                int rl = wr0 + ri*16 + q*4 + reg;
                rpm[rl][w & 1] = m; rps[rl][w & 1] = s;
            }
        }
    }
    // col partials: per ci column, over this wave's 64 rows
    #pragma unroll
    for (int ci = 0; ci < 4; ++ci) {
        float m = acc[0][ci][0], s = 1.f;
        #pragma unroll
        for (int ri = 0; ri < 4; ++ri)
            #pragma unroll
            for (int reg = 0; reg < 4; ++reg)
                if (!(ri == 0 && reg == 0)) online1(m, s, acc[ri][ci][reg]);
        #pragma unroll
        for (int off = 16; off <= 32; off <<= 1) {
            float om = __shfl_xor(m, off, 64);
            float os = __shfl_xor(s, off, 64);
            onmerge(m, s, om, os);
        }
        if (q == 0) {
            int cl = wc0 + ci*16 + ln;
            cpm[cl][w >> 1] = m; cps[cl][w >> 1] = s;
        }
    }
    __syncthreads();
    if (tid < 128) {
        float m = rpm[tid][0], s = rps[tid][0];
        onmerge(m, s, rpm[tid][1], rps[tid][1]);
        size_t o = (size_t)(p * 16 + blockIdx.y) * N + r0 + tid;
        wsf[WS_RPM + o] = m; wsf[WS_RPS + o] = s;
    } else {
        int c = tid - 128;
        float m = cpm[c][0], s = cps[c][0];
        onmerge(m, s, cpm[c][1], cps[c][1]);
        size_t o = (size_t)(p * 16 + blockIdx.x) * N + c0 + c;
        wsf[WS_CPM + o] = m; wsf[WS_CPS + o] = s;
    }
}

// ---- merge 16 chunk partials -> final row/col stats ----
__global__ __launch_bounds__(256) void k_red(float* __restrict__ wsf) {
    int i = blockIdx.x * 256 + threadIdx.x;
    int p = blockIdx.y;
    if (blockIdx.z == 0) {
        float m = wsf[WS_RPM + (size_t)(p*16) * N + i];
        float s = wsf[WS_RPS + (size_t)(p*16) * N + i];
        for (int cb = 1; cb < 16; ++cb)
            onmerge(m, s, wsf[WS_RPM + (size_t)(p*16 + cb) * N + i],
                          wsf[WS_RPS + (size_t)(p*16 + cb) * N + i]);
        wsf[WS_RMAX + p * N + i] = m;
        wsf[WS_RLSE + p * N + i] = logf(s);
    } else {
        float m = wsf[WS_CPM + (size_t)(p*16) * N + i];
        float s = wsf[WS_CPS + (size_t)(p*16) * N + i];
        for (int rb = 1; rb < 16; ++rb)
            onmerge(m, s, wsf[WS_CPM + (size_t)(p*16 + rb) * N + i],
                          wsf[WS_CPS + (size_t)(p*16 + rb) * N + i]);
        wsf[WS_CMAX + p * N + i] = m;
        wsf[WS_CLSE + p * N + i] = logf(s);
    }
}

// ---- final: in-place transform + borders, dword-packed ----
__global__ __launch_bounds__(256) void k_final(u16* __restrict__ out,
                                               const float* __restrict__ wsf) {
    int i = blockIdx.x, p = blockIdx.y;
    int tid = threadIdx.x;
    size_t B0 = ((size_t)p * NO + i) * NO;
    unsigned* up = (unsigned*)out;
    int head = (int)(B0 & 1);
    size_t U0 = (B0 + head) >> 1;
    if (i < N) {
        float rm  = wsf[WS_RMAX + p*N + i];
        float rl  = wsf[WS_RLSE + p*N + i];
        float l0  = wsf[WS_LS0  + p*N + i];
        float ln0 = wsf[WS_LSN0 + p*N + i];
        for (int k = tid; k < 1024; k += 256) {
            unsigned v = up[U0 + k];
            int j0 = 2*k + head;
            float o0, o1;
            {
                float x = b2f((u16)v);
                float a = (x - rm) - rl;
                float b = (x - wsf[WS_CMAX + p*N + j0]) - wsf[WS_CLSE + p*N + j0];
                o0 = fmaxf(fmaxf(a + b, MASKVAL) + (l0 + wsf[WS_LS1 + p*N + j0]), MASKVAL);
            }
            int j1 = j0 + 1;
            if (j1 < N) {
                float x = b2f((u16)(v >> 16));
                float a = (x - rm) - rl;
                float b = (x - wsf[WS_CMAX + p*N + j1]) - wsf[WS_CLSE + p*N + j1];
                o1 = fmaxf(fmaxf(a + b, MASKVAL) + (l0 + wsf[WS_LS1 + p*N + j1]), MASKVAL);
            } else {
                o1 = ln0;
            }
            up[U0 + k] = pk2(o0, o1);
        }
        if (tid == 0) {
            if (head) {
                float x = b2f(out[B0]);
                float a = (x - rm) - rl;
                float b = (x - wsf[WS_CMAX + p*N]) - wsf[WS_CLSE + p*N];
                out[B0] = f2b(fmaxf(fmaxf(a + b, MASKVAL) + (l0 + wsf[WS_LS1 + p*N]), MASKVAL));
            } else {
                out[B0 + N] = f2b(ln0);
            }
        }
    } else {
        for (int k = tid; k < 1024; k += 256) {
            int j0 = 2*k + head;
            float o0 = (j0 < N) ? wsf[WS_LSN1 + p*N + j0] : 0.f;
            int j1 = j0 + 1;
            float o1 = (j1 < N) ? wsf[WS_LSN1 + p*N + j1] : 0.f;
            up[U0 + k] = pk2(o0, o1);
        }
        if (tid == 0) {
            if (head) out[B0] = f2b(wsf[WS_LSN1 + p*N]);
            else      out[B0 + N] = 0;
        }
    }
}

extern "C" void kernel_launch(void* const* d_in, const int* in_sizes, int n_in,
                              void* d_out, int out_size, void* d_ws, size_t ws_size,
                              hipStream_t stream) {
    const float* desc    = (const float*)d_in[0];
    const int*   mask    = (const int*)d_in[1];
    const float* proj_w  = (const float*)d_in[2];
    const float* proj_b  = (const float*)d_in[3];
    const float* match_w = (const float*)d_in[4];
    const float* match_b = (const float*)d_in[5];
    u16*   out = (u16*)d_out;
    float* wsf = (float*)d_ws;
    u16*   mdesc = (u16*)((char*)d_ws + (size_t)WS_F_COUNT * sizeof(float));

    k_proj_mfma<<<dim3(256, 2),    256, 0, stream>>>(desc, proj_w, proj_b, match_w, match_b, mdesc, wsf);
    k_sim_mfma <<<dim3(16, 16, 8), 256, 0, stream>>>(mdesc, mask, out, wsf);
    k_red      <<<dim3(8, 8, 2),   256, 0, stream>>>(wsf);
    k_final    <<<dim3(2049, 8),   256, 0, stream>>>(out, wsf);
}

// Round 8
// 255.186 us; speedup vs baseline: 1.0972x; 1.0972x over previous
//
#include <hip/hip_runtime.h>
#include <math.h>

typedef unsigned short u16;
typedef __attribute__((ext_vector_type(8))) short bf16x8;
typedef __attribute__((ext_vector_type(4))) float f32x4;

#define N 2048
#define D 256
#define PAIRS 8
#define NO 2049
#define NEGMIN  -3.40282347e38f
#define MASKVAL -3.0e38f          // stored sentinel: finite in bf16
#define LDA 72                    // padded LDS row stride (u16)

// ws float region (float offsets within wsf)
#define WS_LS0   0
#define WS_LS1   (1*PAIRS*N)
#define WS_LSN0  (2*PAIRS*N)
#define WS_LSN1  (3*PAIRS*N)
#define WS_RMAX  (4*PAIRS*N)   // unused (kept for layout stability)
#define WS_RLSE  (5*PAIRS*N)   // unused
#define WS_CMAX  (6*PAIRS*N)
#define WS_CLSE  (7*PAIRS*N)
#define WS_RPM   (8*PAIRS*N)               // row partials max [PAIRS][16][N]
#define WS_RPS   (WS_RPM + PAIRS*16*N)
#define WS_CPM   (WS_RPS + PAIRS*16*N)     // col partials max [PAIRS][16][N]
#define WS_CPS   (WS_CPM + PAIRS*16*N)
#define WS_F_COUNT (WS_CPS + PAIRS*16*N)

__device__ __forceinline__ float b2f(u16 u) {
    return __uint_as_float(((unsigned)u) << 16);
}
__device__ __forceinline__ u16 f2b(float f) {  // RNE f32->bf16 (finite in)
    unsigned x = __float_as_uint(f);
    x += 0x7FFFu + ((x >> 16) & 1u);
    return (u16)(x >> 16);
}
__device__ __forceinline__ unsigned pk2(float a, float b) {
    return (unsigned)f2b(a) | ((unsigned)f2b(b) << 16);
}
__device__ __forceinline__ float logsig(float x) {
    return fminf(x, 0.f) - log1pf(expf(-fabsf(x)));
}
__device__ __forceinline__ void online1(float& m, float& s, float x) {
    float nm = fmaxf(m, x);
    float e = __expf(fminf(m, x) - nm);
    s = (x > m) ? s * e + 1.f : s + e;
    m = nm;
}
__device__ __forceinline__ void onmerge(float& m, float& s, float om, float os) {
    float nm = fmaxf(m, om);
    s = s * __expf(m - nm) + os * __expf(om - nm);
    m = nm;
}

// ---- projection GEMM via MFMA + fused matchability ----
__global__ __launch_bounds__(256) void k_proj_mfma(const float* __restrict__ A,
                                                   const float* __restrict__ W,
                                                   const float* __restrict__ bias,
                                                   const float* __restrict__ mw,
                                                   const float* __restrict__ mb,
                                                   u16* __restrict__ mdesc,
                                                   float* __restrict__ wsf) {
    __shared__ u16 As[128 * LDA];
    __shared__ u16 Bs[128 * LDA];
    int r0 = blockIdx.x * 128, c0 = blockIdx.y * 128;
    int tid = threadIdx.x;
    int w = tid >> 6, lane = tid & 63;
    int ln = lane & 15, q = lane >> 4;
    int wr0 = (w >> 1) * 64, wc0 = (w & 1) * 64;
    f32x4 zero = {0.f, 0.f, 0.f, 0.f};
    f32x4 acc[4][4];
    #pragma unroll
    for (int a = 0; a < 4; ++a)
        #pragma unroll
        for (int b = 0; b < 4; ++b) acc[a][b] = zero;
    float mdot[4] = {0.f, 0.f, 0.f, 0.f};
    int domatch = (blockIdx.y == 0);

    for (int kb = 0; kb < D; kb += 64) {
        __syncthreads();
        #pragma unroll
        for (int t = 0; t < 4; ++t) {
            int c = t * 256 + tid;          // chunk (8 bf16 each)
            int row = c >> 3, part = c & 7;
            const float* ap = A + (size_t)(r0 + row) * D + kb + part * 8;
            float4 f0 = *(const float4*)ap;
            float4 f1 = *(const float4*)(ap + 4);
            uint4 va;
            va.x = pk2(f0.x, f0.y); va.y = pk2(f0.z, f0.w);
            va.z = pk2(f1.x, f1.y); va.w = pk2(f1.z, f1.w);
            *(uint4*)&As[row * LDA + part * 8] = va;
            if (domatch) {
                float4 w0 = *(const float4*)(mw + kb + part * 8);
                float4 w1 = *(const float4*)(mw + kb + part * 8 + 4);
                mdot[t] += f0.x*w0.x + f0.y*w0.y + f0.z*w0.z + f0.w*w0.w
                         + f1.x*w1.x + f1.y*w1.y + f1.z*w1.z + f1.w*w1.w;
            }
            const float* bp = W + (size_t)(c0 + row) * D + kb + part * 8;
            float4 g0 = *(const float4*)bp;
            float4 g1 = *(const float4*)(bp + 4);
            uint4 vb;
            vb.x = pk2(g0.x, g0.y); vb.y = pk2(g0.z, g0.w);
            vb.z = pk2(g1.x, g1.y); vb.w = pk2(g1.z, g1.w);
            *(uint4*)&Bs[row * LDA + part * 8] = vb;
        }
        __syncthreads();
        #pragma unroll
        for (int kk = 0; kk < 64; kk += 32) {
            bf16x8 af[4], bf[4];
            #pragma unroll
            for (int ri = 0; ri < 4; ++ri)
                af[ri] = *(const bf16x8*)&As[(wr0 + ri*16 + ln) * LDA + kk + q*8];
            #pragma unroll
            for (int ci = 0; ci < 4; ++ci)
                bf[ci] = *(const bf16x8*)&Bs[(wc0 + ci*16 + ln) * LDA + kk + q*8];
            #pragma unroll
            for (int ri = 0; ri < 4; ++ri)
                #pragma unroll
                for (int ci = 0; ci < 4; ++ci)
                    acc[ri][ci] = __builtin_amdgcn_mfma_f32_16x16x32_bf16(af[ri], bf[ci], acc[ri][ci], 0, 0, 0);
        }
    }
    if (domatch) {
        #pragma unroll
        for (int t = 0; t < 4; ++t) {
            float s = mdot[t];
            s += __shfl_xor(s, 1, 64);
            s += __shfl_xor(s, 2, 64);
            s += __shfl_xor(s, 4, 64);
            if ((tid & 7) == 0) {
                int row_g = r0 + t * 32 + (tid >> 3);
                float m = s + mb[0];
                int b = row_g >> 11;
                int i = row_g & (N - 1);
                int pp = b >> 1, sid = b & 1;
                float ls = logsig(m), lsn = logsig(-m);
                if (sid == 0) { wsf[WS_LS0 + pp*N + i] = ls; wsf[WS_LSN0 + pp*N + i] = lsn; }
                else          { wsf[WS_LS1 + pp*N + i] = ls; wsf[WS_LSN1 + pp*N + i] = lsn; }
            }
        }
    }
    #pragma unroll
    for (int ri = 0; ri < 4; ++ri) {
        #pragma unroll
        for (int reg = 0; reg < 4; ++reg) {
            int row = r0 + wr0 + ri*16 + q*4 + reg;
            #pragma unroll
            for (int ci = 0; ci < 4; ++ci) {
                int col = c0 + wc0 + ci*16 + ln;
                float v = (acc[ri][ci][reg] + bias[col]) * 0.25f;
                mdesc[(size_t)row * D + col] = f2b(v);
            }
        }
    }
}

// ---- similarity GEMM via MFMA + fused masked write + row/col lse partials ----
__global__ __launch_bounds__(256) void k_sim_mfma(const u16* __restrict__ mdesc,
                                                  const int* __restrict__ mask,
                                                  u16* __restrict__ out,
                                                  float* __restrict__ wsf) {
    __shared__ u16 As[128 * LDA];
    __shared__ u16 Bs[128 * LDA];
    __shared__ float rpm[128][2], rps[128][2];
    __shared__ float cpm[128][2], cps[128][2];
    int p = blockIdx.z;
    const u16* A  = mdesc + (size_t)(2*p) * N * D;
    const u16* Bm = mdesc + (size_t)(2*p + 1) * N * D;
    int r0 = blockIdx.x * 128, c0 = blockIdx.y * 128;
    int tid = threadIdx.x;
    int w = tid >> 6, lane = tid & 63;
    int ln = lane & 15, q = lane >> 4;
    int wr0 = (w >> 1) * 64, wc0 = (w & 1) * 64;
    f32x4 zero = {0.f, 0.f, 0.f, 0.f};
    f32x4 acc[4][4];
    #pragma unroll
    for (int a = 0; a < 4; ++a)
        #pragma unroll
        for (int b = 0; b < 4; ++b) acc[a][b] = zero;

    for (int kb = 0; kb < D; kb += 64) {
        __syncthreads();
        #pragma unroll
        for (int t = 0; t < 4; ++t) {
            int c = t * 256 + tid;
            int row = c >> 3, part = c & 7;
            uint4 va = *(const uint4*)(A  + (size_t)(r0 + row) * D + kb + part * 8);
            *(uint4*)&As[row * LDA + part * 8] = va;
            uint4 vb = *(const uint4*)(Bm + (size_t)(c0 + row) * D + kb + part * 8);
            *(uint4*)&Bs[row * LDA + part * 8] = vb;
        }
        __syncthreads();
        #pragma unroll
        for (int kk = 0; kk < 64; kk += 32) {
            bf16x8 af[4], bf[4];
            #pragma unroll
            for (int ri = 0; ri < 4; ++ri)
                af[ri] = *(const bf16x8*)&As[(wr0 + ri*16 + ln) * LDA + kk + q*8];
            #pragma unroll
            for (int ci = 0; ci < 4; ++ci)
                bf[ci] = *(const bf16x8*)&Bs[(wc0 + ci*16 + ln) * LDA + kk + q*8];
            #pragma unroll
            for (int ri = 0; ri < 4; ++ri)
                #pragma unroll
                for (int ci = 0; ci < 4; ++ci)
                    acc[ri][ci] = __builtin_amdgcn_mfma_f32_16x16x32_bf16(af[ri], bf[ci], acc[ri][ci], 0, 0, 0);
        }
    }
    const int* m0 = mask + (size_t)(2*p) * N;
    const int* m1 = mask + (size_t)(2*p + 1) * N;
    u16* outp = out + (size_t)p * NO * NO;
    int mcol[4];
    #pragma unroll
    for (int ci = 0; ci < 4; ++ci) mcol[ci] = m1[c0 + wc0 + ci*16 + ln];
    // apply mask in place + store bf16
    #pragma unroll
    for (int ri = 0; ri < 4; ++ri) {
        #pragma unroll
        for (int reg = 0; reg < 4; ++reg) {
            int row = r0 + wr0 + ri*16 + q*4 + reg;
            int mr = m0[row];
            size_t base = (size_t)row * NO + c0 + wc0 + ln;
            #pragma unroll
            for (int ci = 0; ci < 4; ++ci) {
                float v = (mr && mcol[ci]) ? acc[ri][ci][reg] : MASKVAL;
                acc[ri][ci][reg] = v;
                outp[base + ci*16] = f2b(v);
            }
        }
    }
    // row partials: per (ri,reg) row, over this wave's 64 cols
    #pragma unroll
    for (int ri = 0; ri < 4; ++ri) {
        #pragma unroll
        for (int reg = 0; reg < 4; ++reg) {
            float m = acc[ri][0][reg], s = 1.f;
            online1(m, s, acc[ri][1][reg]);
            online1(m, s, acc[ri][2][reg]);
            online1(m, s, acc[ri][3][reg]);
            #pragma unroll
            for (int off = 1; off <= 8; off <<= 1) {
                float om = __shfl_xor(m, off, 64);
                float os = __shfl_xor(s, off, 64);
                onmerge(m, s, om, os);
            }
            if (ln == 0) {
                int rl = wr0 + ri*16 + q*4 + reg;
                rpm[rl][w & 1] = m; rps[rl][w & 1] = s;
            }
        }
    }
    // col partials: per ci column, over this wave's 64 rows
    #pragma unroll
    for (int ci = 0; ci < 4; ++ci) {
        float m = acc[0][ci][0], s = 1.f;
        #pragma unroll
        for (int ri = 0; ri < 4; ++ri)
            #pragma unroll
            for (int reg = 0; reg < 4; ++reg)
                if (!(ri == 0 && reg == 0)) online1(m, s, acc[ri][ci][reg]);
        #pragma unroll
        for (int off = 16; off <= 32; off <<= 1) {
            float om = __shfl_xor(m, off, 64);
            float os = __shfl_xor(s, off, 64);
            onmerge(m, s, om, os);
        }
        if (q == 0) {
            int cl = wc0 + ci*16 + ln;
            cpm[cl][w >> 1] = m; cps[cl][w >> 1] = s;
        }
    }
    __syncthreads();
    if (tid < 128) {
        float m = rpm[tid][0], s = rps[tid][0];
        onmerge(m, s, rpm[tid][1], rps[tid][1]);
        size_t o = (size_t)(p * 16 + blockIdx.y) * N + r0 + tid;
        wsf[WS_RPM + o] = m; wsf[WS_RPS + o] = s;
    } else {
        int c = tid - 128;
        float m = cpm[c][0], s = cps[c][0];
        onmerge(m, s, cpm[c][1], cps[c][1]);
        size_t o = (size_t)(p * 16 + blockIdx.x) * N + c0 + c;
        wsf[WS_CPM + o] = m; wsf[WS_CPS + o] = s;
    }
}

// ---- merge 16 chunk partials -> final col stats (rows merged in k_final) ----
__global__ __launch_bounds__(256) void k_red(float* __restrict__ wsf) {
    int i = blockIdx.x * 256 + threadIdx.x;
    int p = blockIdx.y;
    float m = wsf[WS_CPM + (size_t)(p*16) * N + i];
    float s = wsf[WS_CPS + (size_t)(p*16) * N + i];
    for (int rb = 1; rb < 16; ++rb)
        onmerge(m, s, wsf[WS_CPM + (size_t)(p*16 + rb) * N + i],
                      wsf[WS_CPS + (size_t)(p*16 + rb) * N + i]);
    wsf[WS_CMAX + p * N + i] = m;
    wsf[WS_CLSE + p * N + i] = logf(s);
}

// ---- final: 8 rows per block; col stats cached in regs across rows ----
__global__ __launch_bounds__(256) void k_final(u16* __restrict__ out,
                                               const float* __restrict__ wsf) {
    int strip = blockIdx.x;     // rows 8*strip .. 8*strip+7 (clipped at NO)
    int p = blockIdx.y;
    int tid = threadIdx.x;
    __shared__ float rm_l[8], rl_l[8], l0_l[8], ln0_l[8];
    // phase A: merge row partials for this strip (threads 0..127; 16 per row)
    if (tid < 128) {
        int r = tid >> 4, cb = tid & 15;
        int i = strip * 8 + r;
        if (i < N) {
            float m = wsf[WS_RPM + (size_t)(p*16 + cb) * N + i];
            float sv = wsf[WS_RPS + (size_t)(p*16 + cb) * N + i];
            #pragma unroll
            for (int off = 1; off <= 8; off <<= 1) {
                float om = __shfl_xor(m, off, 64);
                float os = __shfl_xor(sv, off, 64);
                onmerge(m, sv, om, os);
            }
            if (cb == 0) {
                rm_l[r]  = m;
                rl_l[r]  = logf(sv);
                l0_l[r]  = wsf[WS_LS0  + p*N + i];
                ln0_l[r] = wsf[WS_LSN0 + p*N + i];
            }
        }
    }
    __syncthreads();
    unsigned* up = (unsigned*)out;
    #pragma unroll
    for (int k = 0; k < 4; ++k) {
        int kk = k * 256 + tid;            // uint index within row: 0..1023
        int jc = 2 * kk;                   // cached cols jc, jc+1, jc+2
        float cm0 = wsf[WS_CMAX + p*N + jc];
        float cl0 = wsf[WS_CLSE + p*N + jc];
        float s10 = wsf[WS_LS1  + p*N + jc];
        float cm1 = wsf[WS_CMAX + p*N + jc + 1];
        float cl1 = wsf[WS_CLSE + p*N + jc + 1];
        float s11 = wsf[WS_LS1  + p*N + jc + 1];
        float cm2 = 0.f, cl2 = 0.f, s12 = 0.f;
        if (jc + 2 < N) {
            cm2 = wsf[WS_CMAX + p*N + jc + 2];
            cl2 = wsf[WS_CLSE + p*N + jc + 2];
            s12 = wsf[WS_LS1  + p*N + jc + 2];
        }
        for (int r = 0; r < 8; ++r) {
            int i = strip * 8 + r;
            if (i > N) break;
            size_t B0 = ((size_t)p * NO + i) * NO;
            int head = (p + i) & 1;        // (p*NO + i)*NO mod 2, NO odd
            size_t U0 = (B0 + head) >> 1;
            if (i == N) {                  // border row (strip 256 only)
                int j0 = 2*kk + head;
                float o0 = (j0 < N) ? wsf[WS_LSN1 + p*N + j0] : 0.f;
                int j1 = j0 + 1;
                float o1 = (j1 < N) ? wsf[WS_LSN1 + p*N + j1] : 0.f;
                up[U0 + kk] = pk2(o0, o1);
                if (tid == 0 && k == 0) {
                    if (head) out[B0] = f2b(wsf[WS_LSN1 + p*N]);
                    else      out[B0 + N] = 0;
                }
                continue;
            }
            float rm = rm_l[r], rl = rl_l[r], l0 = l0_l[r], ln0 = ln0_l[r];
            unsigned v = up[U0 + kk];
            float cmA = head ? cm1 : cm0;
            float clA = head ? cl1 : cl0;
            float s1A = head ? s11 : s10;
            float x0 = b2f((u16)v);
            float a0 = (x0 - rm) - rl;
            float b0 = (x0 - cmA) - clA;
            float o0 = fmaxf(fmaxf(a0 + b0, MASKVAL) + (l0 + s1A), MASKVAL);
            float o1;
            int j1 = 2*kk + head + 1;
            if (j1 < N) {
                float cmB = head ? cm2 : cm1;
                float clB = head ? cl2 : cl1;
                float s1B = head ? s12 : s11;
                float x1 = b2f((u16)(v >> 16));
                float a1 = (x1 - rm) - rl;
                float b1 = (x1 - cmB) - clB;
                o1 = fmaxf(fmaxf(a1 + b1, MASKVAL) + (l0 + s1B), MASKVAL);
            } else {
                o1 = ln0;                  // border col packed (head=1 rows)
            }
            up[U0 + kk] = pk2(o0, o1);
            if (tid == 0 && k == 0) {
                if (head) {                // col 0 scalar (not covered by uints)
                    float x = b2f(out[B0]);
                    float a = (x - rm) - rl;
                    float b = (x - wsf[WS_CMAX + p*N]) - wsf[WS_CLSE + p*N];
                    out[B0] = f2b(fmaxf(fmaxf(a + b, MASKVAL) + (l0 + wsf[WS_LS1 + p*N]), MASKVAL));
                } else {                   // border col scalar
                    out[B0 + N] = f2b(ln0);
                }
            }
        }
    }
}

extern "C" void kernel_launch(void* const* d_in, const int* in_sizes, int n_in,
                              void* d_out, int out_size, void* d_ws, size_t ws_size,
                              hipStream_t stream) {
    const float* desc    = (const float*)d_in[0];
    const int*   mask    = (const int*)d_in[1];
    const float* proj_w  = (const float*)d_in[2];
    const float* proj_b  = (const float*)d_in[3];
    const float* match_w = (const float*)d_in[4];
    const float* match_b = (const float*)d_in[5];
    u16*   out = (u16*)d_out;
    float* wsf = (float*)d_ws;
    u16*   mdesc = (u16*)((char*)d_ws + (size_t)WS_F_COUNT * sizeof(float));

    k_proj_mfma<<<dim3(256, 2),    256, 0, stream>>>(desc, proj_w, proj_b, match_w, match_b, mdesc, wsf);
    k_sim_mfma <<<dim3(16, 16, 8), 256, 0, stream>>>(mdesc, mask, out, wsf);
    k_red      <<<dim3(8, 8),      256, 0, stream>>>(wsf);
    k_final    <<<dim3(257, 8),    256, 0, stream>>>(out, wsf);
}